// Round 20
// baseline (39.344 us; speedup 1.0000x reference)
//
#include <hip/hip_runtime.h>
#include <hip/hip_bf16.h>
#include <math.h>
#include <stdint.h>

static constexpr int B = 32, H = 256, N = 512, T = 2048;
static constexpr int TTILE = 64;   // t-tile per fused block
static constexpr int KC = 64;      // n-window width
static constexpr float kLOG_2PI = 1.8378770664093453f;
static constexpr float kLOG2E   = 1.4426950408889634f;
static constexpr float kNEG_BIG = -3.0e38f;
static constexpr float kRANGE_DELTA = 26.0f;  // log2 threshold below max lower-bound

typedef __attribute__((ext_vector_type(8))) short bf16x8;
typedef __attribute__((ext_vector_type(4))) float f32x4;

static __device__ __forceinline__ short f2bf(float f) {
  __hip_bfloat16 h = __float2bfloat16(f);   // HW RNE cvt
  return *reinterpret_cast<short*>(&h);
}

// Kernel 1: per-batch params psg[n] = {c, a2, q2, r}, bstat[b] = {a2max, c_last}.
// w2(n,t) = a2[n] - q2[n](t-c[n])^2; r[n]: w2 >= thr <=> |t-c[n]| <= r[n],
// thr = (a2min - q2max*(dmax/2)^2) - 26.
__global__ void k_prep(const float* __restrict__ dur, const float* __restrict__ vars,
                       const int* __restrict__ lens,
                       float4* __restrict__ psg, float2* __restrict__ bstat) {
  const int b = blockIdx.x;
  const int lane = threadIdx.x;  // 64
  const int L = lens[b];
  float running = 0.f;
  float rc[N / 64], ra2[N / 64], rq2[N / 64];
  float a2max = kNEG_BIG, a2min = -kNEG_BIG, q2min = -kNEG_BIG, q2max = kNEG_BIG;
  float dmax = 0.f, clast = 0.f;
#pragma unroll
  for (int i = 0; i < N / 64; ++i) {
    const int n = i * 64 + lane;
    const float d = dur[b * N + n];
    float x = d;
#pragma unroll
    for (int off = 1; off < 64; off <<= 1) {
      float up = __shfl_up(x, off, 64);
      if (lane >= off) x += up;
    }
    const float cc = running + x - 0.5f * d;
    running += __shfl(x, 63, 64);
    const float v = vars[b * N + n];
    const float a2v = -0.5f * (kLOG_2PI + logf(v)) * kLOG2E;
    const float q2v = 0.5f * kLOG2E / v;
    rc[i] = cc; ra2[i] = a2v; rq2[i] = q2v;
    if (n < L) {
      a2max = fmaxf(a2max, a2v); a2min = fminf(a2min, a2v);
      q2min = fminf(q2min, q2v); q2max = fmaxf(q2max, q2v);
      dmax = fmaxf(dmax, d);
      if (n == L - 1) clast = cc;
    }
  }
#pragma unroll
  for (int off = 32; off; off >>= 1) {
    a2max = fmaxf(a2max, __shfl_xor(a2max, off, 64));
    a2min = fminf(a2min, __shfl_xor(a2min, off, 64));
    q2min = fminf(q2min, __shfl_xor(q2min, off, 64));
    q2max = fmaxf(q2max, __shfl_xor(q2max, off, 64));
    dmax  = fmaxf(dmax,  __shfl_xor(dmax,  off, 64));
    clast = fmaxf(clast, __shfl_xor(clast, off, 64));
  }
  const float dnb = 0.5f * dmax;
  const float m_lower = a2min - q2max * dnb * dnb;
  const float thr = m_lower - kRANGE_DELTA;
#pragma unroll
  for (int i = 0; i < N / 64; ++i) {
    const int n = i * 64 + lane;
    const float rr = sqrtf(fmaxf(ra2[i] - thr, 0.f) / rq2[i]);
    psg[(size_t)b * N + n] = make_float4(rc[i], ra2[i], rq2[i], rr);
  }
  if (lane == 0) bstat[b] = make_float2(a2max, clast);
}

// Kernel 2 (fused, r19 structure + transposed MFMA): 1024 blocks, 256 thr.
// XCD-locality decode: xcd = id & 7 owns b in [4*xcd, 4*xcd+4) -> enc panels
// L2-resident per XCD.
// Near tiles: m = a2max (shift-invariance), per-wave interval-test range.
// Far tiles: stage ps in LDS, exact per-t max + range scans.
// Phase 2: nlo-aligned window loop; B-gen (p bf16) through LDS; enc fragments
// read DIRECTLY from global fp32 (cvt inline). MFMA computes D = p x enc
// (t rows, h cols) so each thread holds 4 CONSECUTIVE t's per fragment ->
// float4 epilogue stores (16/thread, 1KB coalesced per instruction).
__global__ __launch_bounds__(256) void k_fused(
    const float* __restrict__ enc, const float4* __restrict__ psg,
    const int* __restrict__ lens, const float2* __restrict__ bstat,
    float* __restrict__ out) {
  __shared__ short pB[TTILE * KC];   // 8 KB bf16, swizzled [t][k]
  __shared__ float4 ps[N];           // 8 KB (far path only)
  __shared__ float m_lds[TTILE];
  __shared__ __align__(16) float s_lds[TTILE];
  __shared__ int range_sh[2];        // block lo, hi

  // XCD-locality decode: xcd = id & 7, j = id >> 3; b = xcd*4 + (j>>5).
  const int id = blockIdx.x;
  const int jd = id >> 3;
  const int b = (id & 7) * 4 + (jd >> 5);
  const int t0 = (jd & 31) * TTILE;

  const int tid = threadIdx.x;
  const int lane = tid & 63;
  const int wave = tid >> 6;
  const int L = lens[b];
  const float2 bs = bstat[b];
  const float* encb = enc + (size_t)b * H * N;
  const float4* psb = psg + (size_t)b * N;

  if (tid < TTILE) s_lds[tid] = 0.f;
  if (tid == 0) { range_sh[0] = N; range_sh[1] = -1; }
  __syncthreads();

  const bool tile_near = ((float)(t0 + TTILE - 1) <= bs.y);

  if (tile_near) {
    // ---- near: constant shift + interval-test range (2 iterations) ----
    if (tid < TTILE) m_lds[tid] = bs.x;   // m = a2max
    const float tmin = (float)t0, tmax = (float)(t0 + TTILE - 1);
    int lo = N, hi = -1;
#pragma unroll
    for (int rr = 0; rr < 2; ++rr) {
      const int n = rr * 256 + tid;
      const float4 p4 = psb[n];
      if (n < L && (p4.x - p4.w) <= tmax && (p4.x + p4.w) >= tmin) {
        lo = min(lo, n); hi = max(hi, n);
      }
    }
#pragma unroll
    for (int off = 32; off; off >>= 1) {
      lo = min(lo, __shfl_xor(lo, off, 64));
      hi = max(hi, __shfl_xor(hi, off, 64));
    }
    if (lane == 0) { atomicMin(&range_sh[0], lo); atomicMax(&range_sh[1], hi); }
    __syncthreads();
  } else {
    // ---- far: stage ps, exact per-t max (4 thr/t, dual chains) + range ----
    for (int i = tid; i < N; i += 256) ps[i] = psb[i];
    __syncthreads();
    const int tl = tid >> 2, j = tid & 3;
    const float tf = (float)(t0 + tl);
    const int iL = (L + 3) >> 2;
    float mA = kNEG_BIG, mB = kNEG_BIG;
    int i1 = 0;
    for (; i1 + 1 < iL; i1 += 2) {
      const int n1 = i1 * 4 + j, n2 = n1 + 4;
      const float4 p1 = ps[n1];
      const float tc1 = tf - p1.x;
      const float w1 = fmaf(-p1.z, tc1 * tc1, p1.y);
      mA = fmaxf(mA, (n1 < L) ? w1 : kNEG_BIG);
      const float4 p2 = ps[n2];
      const float tc2 = tf - p2.x;
      const float w2 = fmaf(-p2.z, tc2 * tc2, p2.y);
      mB = fmaxf(mB, (n2 < L) ? w2 : kNEG_BIG);
    }
    if (i1 < iL) {
      const int n1 = i1 * 4 + j;
      const float4 p1 = ps[n1];
      const float tc1 = tf - p1.x;
      const float w1 = fmaf(-p1.z, tc1 * tc1, p1.y);
      mA = fmaxf(mA, (n1 < L) ? w1 : kNEG_BIG);
    }
    float m = fmaxf(mA, mB);
    m = fmaxf(m, __shfl_xor(m, 1, 64));
    m = fmaxf(m, __shfl_xor(m, 2, 64));
    if (j == 0) m_lds[tl] = m;

    const float thr = m - kRANGE_DELTA;
    int lo = N, hi = -1;
    for (int i2 = 0; i2 < iL; ++i2) {
      const int n = i2 * 4 + j;
      const float4 p4 = ps[n];
      const float tc = tf - p4.x;
      const float ww = fmaf(-p4.z, tc * tc, p4.y);
      if (n < L && ww >= thr) { lo = min(lo, n); hi = max(hi, n); }
    }
#pragma unroll
    for (int off = 32; off; off >>= 1) {
      lo = min(lo, __shfl_xor(lo, off, 64));
      hi = max(hi, __shfl_xor(hi, off, 64));
    }
    if (lane == 0) { atomicMin(&range_sh[0], lo); atomicMax(&range_sh[1], hi); }
    __syncthreads();
  }

  int nlo = range_sh[0], nhi = range_sh[1];
  if (nhi < 0) { nlo = 0; nhi = L - 1; }   // paranoia fallback
  nlo = max(0, min(nlo, N - 1)); nhi = max(nlo, min(nhi, N - 1));

  f32x4 acc[4][4];
#pragma unroll
  for (int mf = 0; mf < 4; ++mf)
#pragma unroll
    for (int tt = 0; tt < 4; ++tt) acc[mf][tt] = (f32x4){0.f, 0.f, 0.f, 0.f};

  const int l15 = lane & 15;
  const int lhi = lane >> 4;
  const int arow0 = wave * 64 + l15;   // + mf*16

  // ---- Phase 2: nlo-aligned window loop ----
  int wb = nlo & ~3;
  while (true) {
    const int wbc = min(wb, N - KC);   // in-bounds aligned base (mult of 4)
    const int wlo = max(wb, nlo);      // valid low edge (avoid double-count)
    __syncthreads();   // prev window's pB reads done (first iter: no-op cost)
    // stage B: unnormalized p[t][k] bf16 (n = wbc + k) + s[t] accumulation
#pragma unroll
    for (int i = 0; i < 2; ++i) {
      const int flat = i * 256 + tid;       // t*8 + j8
      const int t = flat >> 3, j8 = flat & 7;
      const int nbase = wbc + j8 * 8;
      const int byte = ((t * KC + j8 * 8) * 2) ^ ((t & 7) << 4);
      bf16x8 w;
      float psum = 0.f;
      if (nbase + 7 < wlo || nbase > nhi) {
        w = (bf16x8){0, 0, 0, 0, 0, 0, 0, 0};
      } else {
        const float mt = m_lds[t];
        const float tft = (float)(t0 + t);
#pragma unroll
        for (int jj = 0; jj < 8; ++jj) {
          const int n = nbase + jj;
          const float4 p4 = psb[min(n, nhi)];
          const float tc = tft - p4.x;
          const float w2v = fmaf(-p4.z, tc * tc, p4.y);
          const float pv = (n >= wlo && n <= nhi) ? exp2f(w2v - mt) : 0.f;
          psum += pv;
          w[jj] = f2bf(pv);
        }
      }
      *(bf16x8*)((char*)pB + byte) = w;
      psum += __shfl_xor(psum, 1, 64);
      psum += __shfl_xor(psum, 2, 64);
      psum += __shfl_xor(psum, 4, 64);
      if ((tid & 7) == 0) atomicAdd(&s_lds[t], psum);
    }
    __syncthreads();  // pB + s_lds visible
    // MFMA: enc fragments straight from global fp32 (cvt inline), p from pB.
    // Transposed: D = p (A, t x k) x enc (B, k x h) -> D row = t, col = h.
#pragma unroll
    for (int kk = 0; kk < KC; kk += 32) {
      if (wbc + kk > nhi || wbc + kk + 31 < wlo) continue;
      const int col = wbc + kk + lhi * 8;
      bf16x8 aF[4], bF[4];
#pragma unroll
      for (int mf = 0; mf < 4; ++mf) {
        const float* src = encb + (size_t)(arow0 + mf * 16) * N + col;
        const float4 v0 = *(const float4*)(src);
        const float4 v1 = *(const float4*)(src + 4);
        aF[mf][0] = f2bf(v0.x); aF[mf][1] = f2bf(v0.y);
        aF[mf][2] = f2bf(v0.z); aF[mf][3] = f2bf(v0.w);
        aF[mf][4] = f2bf(v1.x); aF[mf][5] = f2bf(v1.y);
        aF[mf][6] = f2bf(v1.z); aF[mf][7] = f2bf(v1.w);
      }
#pragma unroll
      for (int tt = 0; tt < 4; ++tt) {
        const int t = tt * 16 + l15;
        const int byte = ((t * KC + kk + lhi * 8) * 2) ^ ((t & 7) << 4);
        bF[tt] = *(const bf16x8*)((const char*)pB + byte);
      }
#pragma unroll
      for (int mf = 0; mf < 4; ++mf)
#pragma unroll
        for (int tt = 0; tt < 4; ++tt)
          acc[mf][tt] = __builtin_amdgcn_mfma_f32_16x16x32_bf16(bF[tt], aF[mf], acc[mf][tt], 0, 0, 0);
    }
    if (wbc + KC > nhi) break;
    wb = wbc + KC;
  }

  // ---- Epilogue (transposed D): row(t) = (lane>>4)*4 + r, col(h) = lane&15.
  // Thread holds 4 consecutive t's per fragment -> one float4 store each.
#pragma unroll
  for (int tt = 0; tt < 4; ++tt) {
    const int tbase = tt * 16 + lhi * 4;
    const float4 sv = *(const float4*)&s_lds[tbase];
    const float is0 = 1.0f / sv.x, is1 = 1.0f / sv.y;
    const float is2 = 1.0f / sv.z, is3 = 1.0f / sv.w;
#pragma unroll
    for (int mf = 0; mf < 4; ++mf) {
      const int h = wave * 64 + mf * 16 + l15;
      const float4 o = make_float4(acc[mf][tt][0] * is0, acc[mf][tt][1] * is1,
                                   acc[mf][tt][2] * is2, acc[mf][tt][3] * is3);
      *(float4*)&out[((size_t)(b * H + h)) * T + t0 + tbase] = o;
    }
  }
}

extern "C" void kernel_launch(void* const* d_in, const int* in_sizes, int n_in,
                              void* d_out, int out_size, void* d_ws, size_t ws_size,
                              hipStream_t stream) {
  const float* enc  = (const float*)d_in[0];
  const float* dur  = (const float*)d_in[1];
  const float* vars = (const float*)d_in[2];
  const int*   lens = (const int*)d_in[3];
  float* out = (float*)d_out;

  char* ws = (char*)d_ws;
  float4* psg   = (float4*)ws;               // B*N float4
  float2* bstat = (float2*)(psg + B * N);    // B float2

  k_prep<<<B, 64, 0, stream>>>(dur, vars, lens, psg, bstat);
  k_fused<<<(T / TTILE) * B, 256, 0, stream>>>(enc, psg, lens, bstat, out);
}

// Round 21
// 35.544 us; speedup vs baseline: 1.1069x; 1.1069x over previous
//
#include <hip/hip_runtime.h>
#include <hip/hip_bf16.h>
#include <math.h>
#include <stdint.h>

static constexpr int B = 32, H = 256, N = 512, T = 2048;
static constexpr int TTILE = 64;   // t-tile per fused block
static constexpr int KC = 64;      // n-window width
static constexpr float kLOG_2PI = 1.8378770664093453f;
static constexpr float kLOG2E   = 1.4426950408889634f;
static constexpr float kNEG_BIG = -3.0e38f;
static constexpr float kRANGE_DELTA = 26.0f;  // log2 threshold below max lower-bound

typedef __attribute__((ext_vector_type(8))) short bf16x8;
typedef __attribute__((ext_vector_type(4))) float f32x4;

static __device__ __forceinline__ short f2bf(float f) {
  __hip_bfloat16 h = __float2bfloat16(f);   // HW RNE cvt
  return *reinterpret_cast<short*>(&h);
}

// Kernel 1: per-batch params psg[n] = {c, a2, q2, r}, bstat[b] = {a2max, c_last}.
// w2(n,t) = a2[n] - q2[n](t-c[n])^2; r[n]: w2 >= thr <=> |t-c[n]| <= r[n],
// thr = (a2min - q2max*(dmax/2)^2) - 26.
__global__ void k_prep(const float* __restrict__ dur, const float* __restrict__ vars,
                       const int* __restrict__ lens,
                       float4* __restrict__ psg, float2* __restrict__ bstat) {
  const int b = blockIdx.x;
  const int lane = threadIdx.x;  // 64
  const int L = lens[b];
  float running = 0.f;
  float rc[N / 64], ra2[N / 64], rq2[N / 64];
  float a2max = kNEG_BIG, a2min = -kNEG_BIG, q2min = -kNEG_BIG, q2max = kNEG_BIG;
  float dmax = 0.f, clast = 0.f;
#pragma unroll
  for (int i = 0; i < N / 64; ++i) {
    const int n = i * 64 + lane;
    const float d = dur[b * N + n];
    float x = d;
#pragma unroll
    for (int off = 1; off < 64; off <<= 1) {
      float up = __shfl_up(x, off, 64);
      if (lane >= off) x += up;
    }
    const float cc = running + x - 0.5f * d;
    running += __shfl(x, 63, 64);
    const float v = vars[b * N + n];
    const float a2v = -0.5f * (kLOG_2PI + logf(v)) * kLOG2E;
    const float q2v = 0.5f * kLOG2E / v;
    rc[i] = cc; ra2[i] = a2v; rq2[i] = q2v;
    if (n < L) {
      a2max = fmaxf(a2max, a2v); a2min = fminf(a2min, a2v);
      q2min = fminf(q2min, q2v); q2max = fmaxf(q2max, q2v);
      dmax = fmaxf(dmax, d);
      if (n == L - 1) clast = cc;
    }
  }
#pragma unroll
  for (int off = 32; off; off >>= 1) {
    a2max = fmaxf(a2max, __shfl_xor(a2max, off, 64));
    a2min = fminf(a2min, __shfl_xor(a2min, off, 64));
    q2min = fminf(q2min, __shfl_xor(q2min, off, 64));
    q2max = fmaxf(q2max, __shfl_xor(q2max, off, 64));
    dmax  = fmaxf(dmax,  __shfl_xor(dmax,  off, 64));
    clast = fmaxf(clast, __shfl_xor(clast, off, 64));
  }
  const float dnb = 0.5f * dmax;
  const float m_lower = a2min - q2max * dnb * dnb;
  const float thr = m_lower - kRANGE_DELTA;
#pragma unroll
  for (int i = 0; i < N / 64; ++i) {
    const int n = i * 64 + lane;
    const float rr = sqrtf(fmaxf(ra2[i] - thr, 0.f) / rq2[i]);
    psg[(size_t)b * N + n] = make_float4(rc[i], ra2[i], rq2[i], rr);
  }
  if (lane == 0) bstat[b] = make_float2(a2max, clast);
}

// Kernel 2 (fused, r9 structure + XCD-locality remap): 1024 blocks, 256 thr.
// Block id -> (b, t0) such that XCD (id&7 under round-robin dispatch) owns
// b in [4*xcd, 4*xcd+4): the 4 enc panels (2 MB) stay L2-resident per XCD.
// Near tiles: m = a2max (shift-invariance), per-wave interval-test range.
// Far tiles: stage ps in LDS, exact per-t max + range scans.
// Phase 2: nlo-aligned window loop; B (p bf16) through LDS; A fragments read
// DIRECTLY from global fp32 enc (no LDS round-trip), cvt inline.
__global__ __launch_bounds__(256) void k_fused(
    const float* __restrict__ enc, const float4* __restrict__ psg,
    const int* __restrict__ lens, const float2* __restrict__ bstat,
    float* __restrict__ out) {
  __shared__ short pB[TTILE * KC];   // 8 KB bf16, swizzled [t][k]
  __shared__ float4 ps[N];           // 8 KB (far path only)
  __shared__ float m_lds[TTILE];
  __shared__ float s_lds[TTILE];
  __shared__ int range_sh[2];        // block lo, hi

  // XCD-locality decode: xcd = id & 7, j = id >> 3; b = xcd*4 + (j>>5).
  const int id = blockIdx.x;
  const int jd = id >> 3;
  const int b = (id & 7) * 4 + (jd >> 5);
  const int t0 = (jd & 31) * TTILE;

  const int tid = threadIdx.x;
  const int lane = tid & 63;
  const int wave = tid >> 6;
  const int L = lens[b];
  const float2 bs = bstat[b];
  const float* encb = enc + (size_t)b * H * N;
  const float4* psb = psg + (size_t)b * N;

  if (tid < TTILE) s_lds[tid] = 0.f;
  if (tid == 0) { range_sh[0] = N; range_sh[1] = -1; }
  __syncthreads();

  const bool tile_near = ((float)(t0 + TTILE - 1) <= bs.y);

  if (tile_near) {
    // ---- near: constant shift + interval-test range (2 iterations) ----
    if (tid < TTILE) m_lds[tid] = bs.x;   // m = a2max
    const float tmin = (float)t0, tmax = (float)(t0 + TTILE - 1);
    int lo = N, hi = -1;
#pragma unroll
    for (int rr = 0; rr < 2; ++rr) {
      const int n = rr * 256 + tid;
      const float4 p4 = psb[n];
      if (n < L && (p4.x - p4.w) <= tmax && (p4.x + p4.w) >= tmin) {
        lo = min(lo, n); hi = max(hi, n);
      }
    }
#pragma unroll
    for (int off = 32; off; off >>= 1) {
      lo = min(lo, __shfl_xor(lo, off, 64));
      hi = max(hi, __shfl_xor(hi, off, 64));
    }
    if (lane == 0) { atomicMin(&range_sh[0], lo); atomicMax(&range_sh[1], hi); }
    __syncthreads();
  } else {
    // ---- far: stage ps, exact per-t max (4 thr/t, dual chains) + range ----
    for (int i = tid; i < N; i += 256) ps[i] = psb[i];
    __syncthreads();
    const int tl = tid >> 2, j = tid & 3;
    const float tf = (float)(t0 + tl);
    const int iL = (L + 3) >> 2;
    float mA = kNEG_BIG, mB = kNEG_BIG;
    int i1 = 0;
    for (; i1 + 1 < iL; i1 += 2) {
      const int n1 = i1 * 4 + j, n2 = n1 + 4;
      const float4 p1 = ps[n1];
      const float tc1 = tf - p1.x;
      const float w1 = fmaf(-p1.z, tc1 * tc1, p1.y);
      mA = fmaxf(mA, (n1 < L) ? w1 : kNEG_BIG);
      const float4 p2 = ps[n2];
      const float tc2 = tf - p2.x;
      const float w2 = fmaf(-p2.z, tc2 * tc2, p2.y);
      mB = fmaxf(mB, (n2 < L) ? w2 : kNEG_BIG);
    }
    if (i1 < iL) {
      const int n1 = i1 * 4 + j;
      const float4 p1 = ps[n1];
      const float tc1 = tf - p1.x;
      const float w1 = fmaf(-p1.z, tc1 * tc1, p1.y);
      mA = fmaxf(mA, (n1 < L) ? w1 : kNEG_BIG);
    }
    float m = fmaxf(mA, mB);
    m = fmaxf(m, __shfl_xor(m, 1, 64));
    m = fmaxf(m, __shfl_xor(m, 2, 64));
    if (j == 0) m_lds[tl] = m;

    const float thr = m - kRANGE_DELTA;
    int lo = N, hi = -1;
    for (int i2 = 0; i2 < iL; ++i2) {
      const int n = i2 * 4 + j;
      const float4 p4 = ps[n];
      const float tc = tf - p4.x;
      const float ww = fmaf(-p4.z, tc * tc, p4.y);
      if (n < L && ww >= thr) { lo = min(lo, n); hi = max(hi, n); }
    }
#pragma unroll
    for (int off = 32; off; off >>= 1) {
      lo = min(lo, __shfl_xor(lo, off, 64));
      hi = max(hi, __shfl_xor(hi, off, 64));
    }
    if (lane == 0) { atomicMin(&range_sh[0], lo); atomicMax(&range_sh[1], hi); }
    __syncthreads();
  }

  int nlo = range_sh[0], nhi = range_sh[1];
  if (nhi < 0) { nlo = 0; nhi = L - 1; }   // paranoia fallback
  nlo = max(0, min(nlo, N - 1)); nhi = max(nlo, min(nhi, N - 1));

  f32x4 acc[4][4];
#pragma unroll
  for (int mf = 0; mf < 4; ++mf)
#pragma unroll
    for (int tt = 0; tt < 4; ++tt) acc[mf][tt] = (f32x4){0.f, 0.f, 0.f, 0.f};

  const int l15 = lane & 15;
  const int lhi = lane >> 4;
  const int arow0 = wave * 64 + l15;   // + mf*16

  // ---- Phase 2: nlo-aligned window loop ----
  int wb = nlo & ~3;
  while (true) {
    const int wbc = min(wb, N - KC);   // in-bounds aligned base (mult of 4)
    const int wlo = max(wb, nlo);      // valid low edge (avoid double-count)
    __syncthreads();   // prev window's pB reads done (first iter: no-op cost)
    // stage B: unnormalized p[t][k] bf16 (n = wbc + k) + s[t] accumulation
#pragma unroll
    for (int i = 0; i < 2; ++i) {
      const int flat = i * 256 + tid;       // t*8 + j8
      const int t = flat >> 3, j8 = flat & 7;
      const int nbase = wbc + j8 * 8;
      const int byte = ((t * KC + j8 * 8) * 2) ^ ((t & 7) << 4);
      bf16x8 w;
      float psum = 0.f;
      if (nbase + 7 < wlo || nbase > nhi) {
        w = (bf16x8){0, 0, 0, 0, 0, 0, 0, 0};
      } else {
        const float mt = m_lds[t];
        const float tft = (float)(t0 + t);
#pragma unroll
        for (int jj = 0; jj < 8; ++jj) {
          const int n = nbase + jj;
          const float4 p4 = psb[min(n, nhi)];
          const float tc = tft - p4.x;
          const float w2v = fmaf(-p4.z, tc * tc, p4.y);
          const float pv = (n >= wlo && n <= nhi) ? exp2f(w2v - mt) : 0.f;
          psum += pv;
          w[jj] = f2bf(pv);
        }
      }
      *(bf16x8*)((char*)pB + byte) = w;
      psum += __shfl_xor(psum, 1, 64);
      psum += __shfl_xor(psum, 2, 64);
      psum += __shfl_xor(psum, 4, 64);
      if ((tid & 7) == 0) atomicAdd(&s_lds[t], psum);
    }
    __syncthreads();  // pB + s_lds visible
    // MFMA: A fragments straight from global fp32 (cvt inline), B from pB
#pragma unroll
    for (int kk = 0; kk < KC; kk += 32) {
      if (wbc + kk > nhi || wbc + kk + 31 < wlo) continue;
      const int col = wbc + kk + lhi * 8;
      bf16x8 aF[4], bF[4];
#pragma unroll
      for (int mf = 0; mf < 4; ++mf) {
        const float* src = encb + (size_t)(arow0 + mf * 16) * N + col;
        const float4 v0 = *(const float4*)(src);
        const float4 v1 = *(const float4*)(src + 4);
        aF[mf][0] = f2bf(v0.x); aF[mf][1] = f2bf(v0.y);
        aF[mf][2] = f2bf(v0.z); aF[mf][3] = f2bf(v0.w);
        aF[mf][4] = f2bf(v1.x); aF[mf][5] = f2bf(v1.y);
        aF[mf][6] = f2bf(v1.z); aF[mf][7] = f2bf(v1.w);
      }
#pragma unroll
      for (int tt = 0; tt < 4; ++tt) {
        const int t = tt * 16 + l15;
        const int byte = ((t * KC + kk + lhi * 8) * 2) ^ ((t & 7) << 4);
        bF[tt] = *(const bf16x8*)((const char*)pB + byte);
      }
#pragma unroll
      for (int mf = 0; mf < 4; ++mf)
#pragma unroll
        for (int tt = 0; tt < 4; ++tt)
          acc[mf][tt] = __builtin_amdgcn_mfma_f32_16x16x32_bf16(aF[mf], bF[tt], acc[mf][tt], 0, 0, 0);
    }
    if (wbc + KC > nhi) break;
    wb = wbc + KC;
  }

  // ---- Epilogue: normalize by 1/s[t]; C/D: col(t)=lane&15, row=(lane>>4)*4+r
#pragma unroll
  for (int tt = 0; tt < 4; ++tt) {
    const int t = tt * 16 + l15;
    const float is = 1.0f / s_lds[t];
#pragma unroll
    for (int mf = 0; mf < 4; ++mf) {
      const int h = wave * 64 + mf * 16 + lhi * 4;
#pragma unroll
      for (int r = 0; r < 4; ++r) {
        out[((size_t)(b * H + h + r)) * T + t0 + t] = acc[mf][tt][r] * is;
      }
    }
  }
}

extern "C" void kernel_launch(void* const* d_in, const int* in_sizes, int n_in,
                              void* d_out, int out_size, void* d_ws, size_t ws_size,
                              hipStream_t stream) {
  const float* enc  = (const float*)d_in[0];
  const float* dur  = (const float*)d_in[1];
  const float* vars = (const float*)d_in[2];
  const int*   lens = (const int*)d_in[3];
  float* out = (float*)d_out;

  char* ws = (char*)d_ws;
  float4* psg   = (float4*)ws;               // B*N float4
  float2* bstat = (float2*)(psg + B * N);    // B float2

  k_prep<<<B, 64, 0, stream>>>(dur, vars, lens, psg, bstat);
  k_fused<<<(T / TTILE) * B, 256, 0, stream>>>(enc, psg, lens, bstat, out);
}